// Round 3
// baseline (129.972 us; speedup 1.0000x reference)
//
#include <hip/hip_runtime.h>
#include <hip/hip_bf16.h>
#include <stdint.h>

#define BATCH 8192
#define DIM   512
#define TILE  128
#define BK    64
#define NT    (BATCH / TILE)          // 64 tiles per dim
#define NPAIR (NT * (NT + 1) / 2)     // 2080 upper-triangle tile pairs
#define NXCD  8

// Fb = F_norm * sqrt(log2(e)/T) so acc = Fb·Fbᵀ is already log2-domain logits.
#define FEAT_SCALE 4.5398164f         // sqrt(1.4426950409/0.07)
#define LN2        0.69314718055994531f

typedef __attribute__((ext_vector_type(8))) short short8;
typedef __attribute__((ext_vector_type(4))) float f32x4;

__device__ __forceinline__ void gld_lds16(const void* g, void* l) {
  __builtin_amdgcn_global_load_lds(
      (__attribute__((address_space(1))) void*)(uintptr_t)g,
      (__attribute__((address_space(3))) void*)(uintptr_t)l,
      16, 0, 0);
}

// ---------------------------------------------------------------------------
// Kernel 1: row-normalize fp32 -> bf16 * FEAT_SCALE. One wave per row.
// ---------------------------------------------------------------------------
__global__ __launch_bounds__(256) void normalize_bf16(
    const float* __restrict__ x, __hip_bfloat16* __restrict__ o,
    float* __restrict__ rowsum) {
  const int wv = threadIdx.x >> 6, lane = threadIdx.x & 63;
  const int row = blockIdx.x * 4 + wv;
  if (lane == 0) rowsum[row] = 0.0f;
  const float4* xr = (const float4*)(x + (size_t)row * DIM);
  const float4 v0 = xr[lane];
  const float4 v1 = xr[lane + 64];
  float ss = v0.x * v0.x + v0.y * v0.y + v0.z * v0.z + v0.w * v0.w +
             v1.x * v1.x + v1.y * v1.y + v1.z * v1.z + v1.w * v1.w;
#pragma unroll
  for (int m = 32; m > 0; m >>= 1) ss += __shfl_xor(ss, m, 64);
  const float inv = FEAT_SCALE / fmaxf(sqrtf(ss), 1e-12f);
  ushort4 p0, p1;
  p0.x = __bfloat16_as_ushort(__float2bfloat16(v0.x * inv));
  p0.y = __bfloat16_as_ushort(__float2bfloat16(v0.y * inv));
  p0.z = __bfloat16_as_ushort(__float2bfloat16(v0.z * inv));
  p0.w = __bfloat16_as_ushort(__float2bfloat16(v0.w * inv));
  p1.x = __bfloat16_as_ushort(__float2bfloat16(v1.x * inv));
  p1.y = __bfloat16_as_ushort(__float2bfloat16(v1.y * inv));
  p1.z = __bfloat16_as_ushort(__float2bfloat16(v1.z * inv));
  p1.w = __bfloat16_as_ushort(__float2bfloat16(v1.w * inv));
  ushort4* orow = (ushort4*)(o + (size_t)row * DIM);
  orow[lane]      = p0;
  orow[lane + 64] = p1;
}

// ---------------------------------------------------------------------------
// Kernel 2: symmetric 128x128 bf16 MFMA tiles, upper triangle only.
// acc is log2-domain; epilogue = exp2 + row/col sums. Diag masking only in
// the 64 diagonal tiles; possim only in the 32 tiles with bx==by+32 (there
// the positive sits exactly at lcol==lrow).
// ---------------------------------------------------------------------------
__global__ __launch_bounds__(256, 4) void sim_lse_kernel(
    const __hip_bfloat16* __restrict__ F, float* __restrict__ rowsum,
    float* __restrict__ possim) {
  __shared__ __hip_bfloat16 smem[2 * TILE * BK];  // 32 KB
  __shared__ float rowAcc[TILE];
  __shared__ float colAcc[TILE];

  // XCD-contiguous swizzle: XCD x (t%8 pre-swizzle) gets a contiguous chunk
  // of 260 triangle indices -> A-tile reuse inside one XCD's L2.
  const int t = (blockIdx.x % NXCD) * (NPAIR / NXCD) + blockIdx.x / NXCD;

  int by = (int)((129.0f - sqrtf(129.0f * 129.0f - 8.0f * (float)t)) * 0.5f);
  if (by > NT - 1) by = NT - 1;
  if (by < 0) by = 0;
  while ((by + 1) * (129 - (by + 1)) / 2 <= t) ++by;
  while (by * (129 - by) / 2 > t) --by;
  const int bx = by + (t - by * (129 - by) / 2);
  const bool diagTile = (bx == by);

  const int rowBase = by * TILE;
  const int colBase = bx * TILE;

  const int tid   = threadIdx.x;
  const int lane  = tid & 63;
  const int wv    = tid >> 6;
  const int waveM = wv >> 1;
  const int waveN = wv & 1;
  const int quad  = lane >> 4;
  const int l15   = lane & 15;

  if (tid < TILE) { rowAcc[tid] = 0.0f; colAcc[tid] = 0.0f; }

  f32x4 acc[4][4] = {};

  const int sb = lane & 7;
  const __hip_bfloat16* gA[4];
  const __hip_bfloat16* gB[4];
  char* ldsA[4];
  char* ldsB[4];
#pragma unroll
  for (int c = 0; c < 4; ++c) {
    const int sRow = wv * 32 + c * 8 + (lane >> 3);
    const int g = sb ^ (sRow & 7);
    gA[c] = F + (size_t)(rowBase + sRow) * DIM + g * 8;
    gB[c] = F + (size_t)(colBase + sRow) * DIM + g * 8;
    ldsA[c] = (char*)smem + (wv * 4 + c) * 1024;
    ldsB[c] = (char*)smem + 16384 + (wv * 4 + c) * 1024;
  }

  int aOff[4], bOff[4];
#pragma unroll
  for (int i = 0; i < 4; ++i) {
    const int Ra = waveM * 64 + i * 16 + l15;
    aOff[i] = Ra * 128 + (quad ^ (Ra & 7)) * 16;
    const int Rb = waveN * 64 + i * 16 + l15;
    bOff[i] = 16384 + Rb * 128 + (quad ^ (Rb & 7)) * 16;
  }
  char* sbase = (char*)smem;

  for (int k0 = 0; k0 < DIM; k0 += BK) {
#pragma unroll
    for (int c = 0; c < 4; ++c) {
      gld_lds16(gA[c] + k0, ldsA[c]);
      gld_lds16(gB[c] + k0, ldsB[c]);
    }
    __syncthreads();

    short8 a[4], b[4];
#pragma unroll
    for (int i = 0; i < 4; ++i) {
      a[i] = *(const short8*)(sbase + aOff[i]);
      b[i] = *(const short8*)(sbase + bOff[i]);
    }
#pragma unroll
    for (int mi = 0; mi < 4; ++mi)
#pragma unroll
      for (int ni = 0; ni < 4; ++ni)
        acc[mi][ni] =
            __builtin_amdgcn_mfma_f32_16x16x32_bf16(a[mi], b[ni], acc[mi][ni], 0, 0, 0);
#pragma unroll
    for (int i = 0; i < 4; ++i) {
      a[i] = *(const short8*)(sbase + (aOff[i] ^ 64));
      b[i] = *(const short8*)(sbase + (bOff[i] ^ 64));
    }
#pragma unroll
    for (int mi = 0; mi < 4; ++mi)
#pragma unroll
      for (int ni = 0; ni < 4; ++ni)
        acc[mi][ni] =
            __builtin_amdgcn_mfma_f32_16x16x32_bf16(a[mi], b[ni], acc[mi][ni], 0, 0, 0);
    __syncthreads();
  }

  // --- epilogue ---
  if (diagTile) {
#pragma unroll
    for (int mi = 0; mi < 4; ++mi) {
#pragma unroll
      for (int r = 0; r < 4; ++r) {
        const int lrow = waveM * 64 + mi * 16 + quad * 4 + r;
        float rsum = 0.0f;
#pragma unroll
        for (int ni = 0; ni < 4; ++ni) {
          const int lcol = waveN * 64 + ni * 16 + l15;
          rsum += (lcol == lrow) ? 0.0f : exp2f(acc[mi][ni][r]);
        }
#pragma unroll
        for (int m = 1; m < 16; m <<= 1) rsum += __shfl_xor(rsum, m, 64);
        if (l15 == 0) atomicAdd(&rowAcc[lrow], rsum);
      }
    }
  } else {
    const bool hasPos = (bx == by + 32);
    float colpart[4] = {0.0f, 0.0f, 0.0f, 0.0f};
#pragma unroll
    for (int mi = 0; mi < 4; ++mi) {
#pragma unroll
      for (int r = 0; r < 4; ++r) {
        const int lrow = waveM * 64 + mi * 16 + quad * 4 + r;
        float rsum = 0.0f;
#pragma unroll
        for (int ni = 0; ni < 4; ++ni) {
          const float s = acc[mi][ni][r];
          const float e = exp2f(s);
          rsum += e;
          colpart[ni] += e;
          if (hasPos) {
            const int lcol = waveN * 64 + ni * 16 + l15;
            if (lcol == lrow) {
              const int gi = rowBase + lrow;   // by<32 -> no wraparound
              possim[gi] = s;
              possim[gi + 4096] = s;
            }
          }
        }
#pragma unroll
        for (int m = 1; m < 16; m <<= 1) rsum += __shfl_xor(rsum, m, 64);
        if (l15 == 0) atomicAdd(&rowAcc[lrow], rsum);
      }
    }
#pragma unroll
    for (int ni = 0; ni < 4; ++ni) {
      float c = colpart[ni];
      c += __shfl_xor(c, 16, 64);
      c += __shfl_xor(c, 32, 64);
      if (quad == 0) atomicAdd(&colAcc[waveN * 64 + ni * 16 + l15], c);
    }
  }
  __syncthreads();
  if (tid < TILE) {
    atomicAdd(&rowsum[rowBase + tid], rowAcc[tid]);
    if (!diagTile) atomicAdd(&rowsum[colBase + tid], colAcc[tid]);
  }
}

// ---------------------------------------------------------------------------
// Kernel 3: loss = mean_i( log(rowsum_i) - possim_i * ln2 )
// ---------------------------------------------------------------------------
__global__ __launch_bounds__(1024) void finalize_kernel(
    const float* __restrict__ rowsum, const float* __restrict__ possim,
    float* __restrict__ out) {
  float acc = 0.0f;
  for (int i = threadIdx.x; i < BATCH; i += 1024)
    acc += __logf(rowsum[i]) - possim[i] * LN2;
#pragma unroll
  for (int m = 32; m > 0; m >>= 1) acc += __shfl_xor(acc, m, 64);
  __shared__ float ws[16];
  const int lane = threadIdx.x & 63, wv = threadIdx.x >> 6;
  if (lane == 0) ws[wv] = acc;
  __syncthreads();
  if (threadIdx.x == 0) {
    float tot = 0.0f;
#pragma unroll
    for (int k = 0; k < 16; ++k) tot += ws[k];
    out[0] = tot * (1.0f / (float)BATCH);
  }
}

extern "C" void kernel_launch(void* const* d_in, const int* in_sizes, int n_in,
                              void* d_out, int out_size, void* d_ws, size_t ws_size,
                              hipStream_t stream) {
  const float* x = (const float*)d_in[0];
  float* out = (float*)d_out;

  __hip_bfloat16* Fb = (__hip_bfloat16*)d_ws;
  float* rowsum = (float*)((char*)d_ws + (size_t)BATCH * DIM * sizeof(__hip_bfloat16));
  float* possim = rowsum + BATCH;

  normalize_bf16<<<BATCH / 4, 256, 0, stream>>>(x, Fb, rowsum);
  sim_lse_kernel<<<NPAIR, 256, 0, stream>>>(Fb, rowsum, possim);
  finalize_kernel<<<1, 1024, 0, stream>>>(rowsum, possim, out);
}

// Round 4
// 111.676 us; speedup vs baseline: 1.1638x; 1.1638x over previous
//
#include <hip/hip_runtime.h>
#include <hip/hip_bf16.h>
#include <stdint.h>

#define BATCH 8192
#define DIM   512
#define TILE  128
#define BK    64
#define NT    (BATCH / TILE)          // 64 tiles per dim
#define NPAIR (NT * (NT + 1) / 2)     // 2080 upper-triangle tile pairs

// Fb = F_norm * sqrt(log2(e)/T) so acc = Fb·Fbᵀ is already log2-domain logits.
#define FEAT_SCALE 4.5398164f         // sqrt(1.4426950409/0.07)
#define LN2        0.69314718055994531f

typedef __attribute__((ext_vector_type(8))) short short8;
typedef __attribute__((ext_vector_type(4))) float f32x4;

__device__ __forceinline__ void gld_lds16(const void* g, void* l) {
  __builtin_amdgcn_global_load_lds(
      (__attribute__((address_space(1))) void*)(uintptr_t)g,
      (__attribute__((address_space(3))) void*)(uintptr_t)l,
      16, 0, 0);
}

// ---------------------------------------------------------------------------
// Kernel 1: row-normalize fp32 -> bf16 * FEAT_SCALE. One wave per row.
// ---------------------------------------------------------------------------
__global__ __launch_bounds__(256) void normalize_bf16(
    const float* __restrict__ x, __hip_bfloat16* __restrict__ o,
    float* __restrict__ rowsum) {
  const int wv = threadIdx.x >> 6, lane = threadIdx.x & 63;
  const int row = blockIdx.x * 4 + wv;
  if (lane == 0) rowsum[row] = 0.0f;
  const float4* xr = (const float4*)(x + (size_t)row * DIM);
  const float4 v0 = xr[lane];
  const float4 v1 = xr[lane + 64];
  float ss = v0.x * v0.x + v0.y * v0.y + v0.z * v0.z + v0.w * v0.w +
             v1.x * v1.x + v1.y * v1.y + v1.z * v1.z + v1.w * v1.w;
#pragma unroll
  for (int m = 32; m > 0; m >>= 1) ss += __shfl_xor(ss, m, 64);
  const float inv = FEAT_SCALE / fmaxf(sqrtf(ss), 1e-12f);
  ushort4 p0, p1;
  p0.x = __bfloat16_as_ushort(__float2bfloat16(v0.x * inv));
  p0.y = __bfloat16_as_ushort(__float2bfloat16(v0.y * inv));
  p0.z = __bfloat16_as_ushort(__float2bfloat16(v0.z * inv));
  p0.w = __bfloat16_as_ushort(__float2bfloat16(v0.w * inv));
  p1.x = __bfloat16_as_ushort(__float2bfloat16(v1.x * inv));
  p1.y = __bfloat16_as_ushort(__float2bfloat16(v1.y * inv));
  p1.z = __bfloat16_as_ushort(__float2bfloat16(v1.z * inv));
  p1.w = __bfloat16_as_ushort(__float2bfloat16(v1.w * inv));
  ushort4* orow = (ushort4*)(o + (size_t)row * DIM);
  orow[lane]      = p0;
  orow[lane + 64] = p1;
}

// ---------------------------------------------------------------------------
// Kernel 2: symmetric 128x128 bf16 MFMA tiles, upper triangle, NATURAL block
// order (by-major: co-resident blocks share `by` so rowsum atomics merge at
// the coherence point — the R3 XCD swizzle blew WRITE_SIZE up 16x).
// Epilogue: exp2 (log2-domain acc), per-lane partials -> LDS transpose
// (overlaid on the dead staging buffer) -> 256-thread strided sum -> one
// global atomic per row-half. Col sums (symmetry credit) via 2-round
// butterfly + LDS combine.
// ---------------------------------------------------------------------------
__global__ __launch_bounds__(256, 4) void sim_lse_kernel(
    const __hip_bfloat16* __restrict__ F, float* __restrict__ rowsum,
    float* __restrict__ possim) {
  __shared__ __hip_bfloat16 smem[2 * TILE * BK];  // 32 KB staging; reused by epilogue
  __shared__ float colAcc[TILE];

  const int t = blockIdx.x;
  int by = (int)((129.0f - sqrtf(129.0f * 129.0f - 8.0f * (float)t)) * 0.5f);
  if (by > NT - 1) by = NT - 1;
  if (by < 0) by = 0;
  while ((by + 1) * (129 - (by + 1)) / 2 <= t) ++by;
  while (by * (129 - by) / 2 > t) --by;
  const int bx = by + (t - by * (129 - by) / 2);
  const bool diagTile = (bx == by);

  const int rowBase = by * TILE;
  const int colBase = bx * TILE;

  const int tid   = threadIdx.x;
  const int lane  = tid & 63;
  const int wv    = tid >> 6;
  const int waveM = wv >> 1;
  const int waveN = wv & 1;
  const int quad  = lane >> 4;
  const int l15   = lane & 15;

  if (tid < TILE) colAcc[tid] = 0.0f;

  f32x4 acc[4][4] = {};

  const int sb = lane & 7;
  const __hip_bfloat16* gA[4];
  const __hip_bfloat16* gB[4];
  char* ldsA[4];
  char* ldsB[4];
#pragma unroll
  for (int c = 0; c < 4; ++c) {
    const int sRow = wv * 32 + c * 8 + (lane >> 3);
    const int g = sb ^ (sRow & 7);
    gA[c] = F + (size_t)(rowBase + sRow) * DIM + g * 8;
    gB[c] = F + (size_t)(colBase + sRow) * DIM + g * 8;
    ldsA[c] = (char*)smem + (wv * 4 + c) * 1024;
    ldsB[c] = (char*)smem + 16384 + (wv * 4 + c) * 1024;
  }

  int aOff[4], bOff[4];
#pragma unroll
  for (int i = 0; i < 4; ++i) {
    const int Ra = waveM * 64 + i * 16 + l15;
    aOff[i] = Ra * 128 + (quad ^ (Ra & 7)) * 16;
    const int Rb = waveN * 64 + i * 16 + l15;
    bOff[i] = 16384 + Rb * 128 + (quad ^ (Rb & 7)) * 16;
  }
  char* sbase = (char*)smem;

  for (int k0 = 0; k0 < DIM; k0 += BK) {
#pragma unroll
    for (int c = 0; c < 4; ++c) {
      gld_lds16(gA[c] + k0, ldsA[c]);
      gld_lds16(gB[c] + k0, ldsB[c]);
    }
    __syncthreads();

    short8 a[4], b[4];
#pragma unroll
    for (int i = 0; i < 4; ++i) {
      a[i] = *(const short8*)(sbase + aOff[i]);
      b[i] = *(const short8*)(sbase + bOff[i]);
    }
#pragma unroll
    for (int mi = 0; mi < 4; ++mi)
#pragma unroll
      for (int ni = 0; ni < 4; ++ni)
        acc[mi][ni] =
            __builtin_amdgcn_mfma_f32_16x16x32_bf16(a[mi], b[ni], acc[mi][ni], 0, 0, 0);
#pragma unroll
    for (int i = 0; i < 4; ++i) {
      a[i] = *(const short8*)(sbase + (aOff[i] ^ 64));
      b[i] = *(const short8*)(sbase + (bOff[i] ^ 64));
    }
#pragma unroll
    for (int mi = 0; mi < 4; ++mi)
#pragma unroll
      for (int ni = 0; ni < 4; ++ni)
        acc[mi][ni] =
            __builtin_amdgcn_mfma_f32_16x16x32_bf16(a[mi], b[ni], acc[mi][ni], 0, 0, 0);
    __syncthreads();   // after this, smem staging data is dead -> reuse below
  }

  // --- epilogue ---
  // redBuf overlays smem: [wn][strip][l15][68 dw], 2*2*16*68*4 = 17408 B.
  // Stride 68 dw keeps 16B alignment and spreads b128 writes across all banks.
  float* redBuf = (float*)smem;
  f32x4 rsumv[4] = {};                 // per-lane row partials (rows mi*16+quad*4+r)
  float colpart[4] = {0.0f, 0.0f, 0.0f, 0.0f};

  if (diagTile) {
#pragma unroll
    for (int mi = 0; mi < 4; ++mi)
#pragma unroll
      for (int ni = 0; ni < 4; ++ni)
#pragma unroll
        for (int r = 0; r < 4; ++r) {
          const int rl = waveM * 64 + mi * 16 + quad * 4 + r;
          const int cl = waveN * 64 + ni * 16 + l15;
          rsumv[mi][r] += (cl == rl) ? 0.0f : exp2f(acc[mi][ni][r]);
        }
  } else {
    const bool hasPos = (bx == by + 32);
#pragma unroll
    for (int mi = 0; mi < 4; ++mi)
#pragma unroll
      for (int ni = 0; ni < 4; ++ni)
#pragma unroll
        for (int r = 0; r < 4; ++r) {
          const float s = acc[mi][ni][r];
          const float e = exp2f(s);
          rsumv[mi][r] += e;
          colpart[ni] += e;
          if (hasPos) {
            const int rl = waveM * 64 + mi * 16 + quad * 4 + r;
            const int cl = waveN * 64 + ni * 16 + l15;
            if (cl == rl) {
              const int gi = rowBase + rl;
              possim[gi] = s;
              possim[gi + 4096] = s;
            }
          }
        }
  }

  // transpose-store row partials: lane -> [waveN][waveM][l15][mi*16+quad*4 .. +3]
  {
    float* wbase = redBuf + ((waveN * 2 + waveM) * 16 + l15) * 68 + quad * 4;
#pragma unroll
    for (int mi = 0; mi < 4; ++mi)
      *(f32x4*)(wbase + mi * 16) = rsumv[mi];
  }

  // col sums (symmetry credit): reduce over quads, combine waveM pair in LDS
  if (!diagTile) {
#pragma unroll
    for (int ni = 0; ni < 4; ++ni) {
      float c = colpart[ni];
      c += __shfl_xor(c, 16, 64);
      c += __shfl_xor(c, 32, 64);
      if (quad == 0) atomicAdd(&colAcc[waveN * 64 + ni * 16 + l15], c);
    }
  }
  __syncthreads();

  // 256 threads: each sums one (row, waveN-half) = 16 strided floats
  {
    const int wn = tid >> 7, r = tid & 127;
    const int strip = r >> 6, rl = r & 63;
    const float* base = redBuf + ((wn * 2 + strip) * 16) * 68 + rl;
    float s = 0.0f;
#pragma unroll
    for (int j = 0; j < 16; ++j) s += base[j * 68];
    atomicAdd(&rowsum[rowBase + r], s);
  }
  if (tid < TILE && !diagTile)
    atomicAdd(&rowsum[colBase + tid], colAcc[tid]);
}

// ---------------------------------------------------------------------------
// Kernel 3: loss = mean_i( log(rowsum_i) - possim_i * ln2 )
// ---------------------------------------------------------------------------
__global__ __launch_bounds__(1024) void finalize_kernel(
    const float* __restrict__ rowsum, const float* __restrict__ possim,
    float* __restrict__ out) {
  float acc = 0.0f;
  for (int i = threadIdx.x; i < BATCH; i += 1024)
    acc += __logf(rowsum[i]) - possim[i] * LN2;
#pragma unroll
  for (int m = 32; m > 0; m >>= 1) acc += __shfl_xor(acc, m, 64);
  __shared__ float ws[16];
  const int lane = threadIdx.x & 63, wv = threadIdx.x >> 6;
  if (lane == 0) ws[wv] = acc;
  __syncthreads();
  if (threadIdx.x == 0) {
    float tot = 0.0f;
#pragma unroll
    for (int k = 0; k < 16; ++k) tot += ws[k];
    out[0] = tot * (1.0f / (float)BATCH);
  }
}

extern "C" void kernel_launch(void* const* d_in, const int* in_sizes, int n_in,
                              void* d_out, int out_size, void* d_ws, size_t ws_size,
                              hipStream_t stream) {
  const float* x = (const float*)d_in[0];
  float* out = (float*)d_out;

  __hip_bfloat16* Fb = (__hip_bfloat16*)d_ws;
  float* rowsum = (float*)((char*)d_ws + (size_t)BATCH * DIM * sizeof(__hip_bfloat16));
  float* possim = rowsum + BATCH;

  normalize_bf16<<<BATCH / 4, 256, 0, stream>>>(x, Fb, rowsum);
  sim_lse_kernel<<<NPAIR, 256, 0, stream>>>(Fb, rowsum, possim);
  finalize_kernel<<<1, 1024, 0, stream>>>(rowsum, possim, out);
}